// Round 2
// baseline (131.693 us; speedup 1.0000x reference)
//
#include <hip/hip_runtime.h>
#include <hip/hip_bf16.h>

#define B_   16384
#define KIN  512
#define NE   8
#define HE   256
#define NT   2
#define NO   64
#define NCOL 2048  // NE*HE

using f32x4  = __attribute__((ext_vector_type(4))) float;
using short8 = __attribute__((ext_vector_type(8))) short;

__device__ __forceinline__ float bf2f(unsigned short u) {
    union { unsigned int i; float f; } c; c.i = ((unsigned int)u) << 16; return c.f;
}
__device__ __forceinline__ unsigned short f2bf(float f) {
    union { __hip_bfloat16 h; unsigned short u; } c; c.h = __float2bfloat16(f); return c.u;
}

// ---------------- K1: X fp32 -> bf16 ----------------
__global__ __launch_bounds__(256) void k_cvt_x(const float* __restrict__ x,
                                               unsigned short* __restrict__ xb) {
    int i = blockIdx.x * 256 + threadIdx.x;          // 8-elem chunk id
    const float4* x4 = (const float4*)x;
    float4 a = x4[2 * i], b = x4[2 * i + 1];
    union { uint4 v; unsigned short s[8]; } o;
    o.s[0] = f2bf(a.x); o.s[1] = f2bf(a.y); o.s[2] = f2bf(a.z); o.s[3] = f2bf(a.w);
    o.s[4] = f2bf(b.x); o.s[5] = f2bf(b.y); o.s[6] = f2bf(b.z); o.s[7] = f2bf(b.w);
    ((uint4*)xb)[i] = o.v;
}

// ---------------- K2: We [E][K][H] fp32 -> Wb [E*H][K] bf16 (transpose) ----------------
__global__ __launch_bounds__(256) void k_cvt_we(const float* __restrict__ We,
                                                unsigned short* __restrict__ Wb) {
    __shared__ float tile[64][65];
    int bid = blockIdx.x;
    int e = bid >> 5, rem = bid & 31, kt = rem >> 2, ht = rem & 3;
    int tid = threadIdx.x;
    const float* src = We + e * (KIN * HE) + (kt * 64) * HE + ht * 64;
    for (int it = 0; it < 16; ++it) {
        int idx = tid + it * 256;
        int i = idx >> 6, j = idx & 63;              // i = k-sub, j = h-sub
        tile[i][j] = src[i * HE + j];
    }
    __syncthreads();
    unsigned short* dst = Wb + (size_t)(e * HE + ht * 64) * KIN + kt * 64;
    for (int it = 0; it < 16; ++it) {
        int idx = tid + it * 256;
        int i = idx >> 6, j = idx & 63;              // i = h-sub, j = k-sub
        dst[i * KIN + j] = f2bf(tile[j][i]);
    }
}

// ---------------- K2b: Wt [T][HE][NO] fp32 -> WtT [T][NO][HE] bf16 ----------------
__global__ __launch_bounds__(256) void k_cvt_wt(const float* __restrict__ Wt,
                                                unsigned short* __restrict__ WtT) {
    __shared__ float tile[64][65];
    int bid = blockIdx.x;
    int t = bid >> 2, kt = bid & 3, k0 = kt * 64;
    int tid = threadIdx.x;
    const float* src = Wt + t * (HE * NO) + k0 * NO;
    for (int it = 0; it < 16; ++it) {
        int idx = tid + it * 256;
        int i = idx >> 6, j = idx & 63;              // i = k-sub, j = o
        tile[i][j] = src[i * NO + j];
    }
    __syncthreads();
    unsigned short* dst = WtT + (size_t)t * NO * HE + k0;
    for (int it = 0; it < 16; ++it) {
        int idx = tid + it * 256;
        int o = idx >> 6, j = idx & 63;              // o-row, j = k-sub
        dst[o * HE + j] = f2bf(tile[j][o]);
    }
}

// ---------------- K3: gates = softmax(x @ Wg + bg) -> [B][T*E] fp32 ----------------
__global__ __launch_bounds__(256) void k_gates(const float* __restrict__ xv,
                                               const float* __restrict__ Wg,
                                               const float* __restrict__ bg,
                                               float* __restrict__ gates) {
    int tid = threadIdx.x;
    int lane = tid & 63;
    int wav = tid >> 6;
    int row = blockIdx.x * 16 + wav * 4 + (lane >> 4);
    int sub = lane & 15;                              // t*8+e
    int t = sub >> 3, e = sub & 7;
    const float* xr = xv + (size_t)row * KIN;
    const float* wg = Wg + t * (KIN * NE) + e;
    float acc = bg[sub];
    #pragma unroll 4
    for (int k = 0; k < KIN; ++k)
        acc += xr[k] * wg[k * NE];
    float m = acc;
    m = fmaxf(m, __shfl_xor(m, 1, 8));
    m = fmaxf(m, __shfl_xor(m, 2, 8));
    m = fmaxf(m, __shfl_xor(m, 4, 8));
    float p = __expf(acc - m);
    float s = p;
    s += __shfl_xor(s, 1, 8);
    s += __shfl_xor(s, 2, 8);
    s += __shfl_xor(s, 4, 8);
    gates[row * 16 + sub] = p / s;
}

// ---------------- K4: experts GEMM  H = relu(Xb @ Wb^T + be), bf16 out ----------------
__global__ __launch_bounds__(256) void k_experts(const unsigned short* __restrict__ Xb,
                                                 const unsigned short* __restrict__ Wb,
                                                 const float* __restrict__ be,
                                                 unsigned short* __restrict__ H) {
    __shared__ __align__(16) unsigned short As[128][72];
    __shared__ __align__(16) unsigned short Bs[128][72];
    int tid = threadIdx.x;
    int lane = tid & 63, wav = tid >> 6;
    int wr = wav >> 1, wc = wav & 1;
    int m0 = blockIdx.y * 128, n0 = blockIdx.x * 128;
    int l15 = lane & 15, l4 = lane >> 4;

    f32x4 acc[4][4];
    f32x4 z = {0.f, 0.f, 0.f, 0.f};
    for (int i = 0; i < 4; ++i)
        for (int j = 0; j < 4; ++j) acc[i][j] = z;

    for (int kt = 0; kt < 8; ++kt) {
        int k0 = kt * 64;
        __syncthreads();
        #pragma unroll
        for (int it = 0; it < 4; ++it) {
            int c = tid + it * 256;
            int row = c >> 3, kc = (c & 7) * 8;
            *(uint4*)(&As[row][kc]) = *(const uint4*)(Xb + (size_t)(m0 + row) * KIN + k0 + kc);
            *(uint4*)(&Bs[row][kc]) = *(const uint4*)(Wb + (size_t)(n0 + row) * KIN + k0 + kc);
        }
        __syncthreads();
        #pragma unroll
        for (int kk = 0; kk < 2; ++kk) {
            short8 a[4], b[4];
            int kcol = kk * 32 + l4 * 8;
            #pragma unroll
            for (int mf = 0; mf < 4; ++mf)
                a[mf] = *(const short8*)(&As[wr * 64 + mf * 16 + l15][kcol]);
            #pragma unroll
            for (int nf = 0; nf < 4; ++nf)
                b[nf] = *(const short8*)(&Bs[wc * 64 + nf * 16 + l15][kcol]);
            #pragma unroll
            for (int mf = 0; mf < 4; ++mf)
                #pragma unroll
                for (int nf = 0; nf < 4; ++nf)
                    acc[mf][nf] = __builtin_amdgcn_mfma_f32_16x16x32_bf16(a[mf], b[nf], acc[mf][nf], 0, 0, 0);
        }
    }
    #pragma unroll
    for (int nf = 0; nf < 4; ++nf) {
        int col = n0 + wc * 64 + nf * 16 + l15;
        float bias = be[col];
        #pragma unroll
        for (int mf = 0; mf < 4; ++mf) {
            int rbase = m0 + wr * 64 + mf * 16 + l4 * 4;
            #pragma unroll
            for (int r = 0; r < 4; ++r) {
                float v = acc[mf][nf][r] + bias;
                v = fmaxf(v, 0.f);
                H[(size_t)(rbase + r) * NCOL + col] = f2bf(v);
            }
        }
    }
}

// ---------------- K5a: TI[t][b][h] = sum_e gates[b][t][e] * H[b][e*256+h] ----------------
__global__ __launch_bounds__(256) void k_mix(const unsigned short* __restrict__ H,
                                             const float* __restrict__ gates,
                                             unsigned short* __restrict__ TI) {
    int tid = threadIdx.x;
    int lane = tid & 63, wav = tid >> 6;
    int row = blockIdx.x * 4 + wav;
    int t = lane >> 5, h0 = (lane & 31) * 8;
    const float4* g4 = (const float4*)(gates + row * 16 + t * 8);
    float4 ga = g4[0], gb = g4[1];
    float g[8] = {ga.x, ga.y, ga.z, ga.w, gb.x, gb.y, gb.z, gb.w};
    float acc[8] = {0, 0, 0, 0, 0, 0, 0, 0};
    const uint4* hrow = (const uint4*)(H + (size_t)row * NCOL);
    #pragma unroll
    for (int e = 0; e < 8; ++e) {
        uint4 v = hrow[(e * HE + h0) >> 3];
        unsigned short* s = (unsigned short*)&v;
        #pragma unroll
        for (int j = 0; j < 8; ++j)
            acc[j] += g[e] * bf2f(s[j]);
    }
    union { uint4 v; unsigned short s[8]; } o;
    #pragma unroll
    for (int j = 0; j < 8; ++j) o.s[j] = f2bf(acc[j]);
    *(uint4*)(TI + ((size_t)t * B_ + row) * HE + h0) = o.v;
}

// ---------------- K5b: out[t] = sigmoid(TI_t @ Wt_t + bt_t), fp32 out ----------------
__global__ __launch_bounds__(256) void k_tower(const unsigned short* __restrict__ TI,
                                               const unsigned short* __restrict__ WtT,
                                               const float* __restrict__ bt,
                                               float* __restrict__ out) {
    __shared__ __align__(16) unsigned short As[64][264];
    __shared__ __align__(16) unsigned short Ws[64][264];
    int tid = threadIdx.x;
    int lane = tid & 63, wav = tid >> 6;
    int t = blockIdx.y;
    int m0 = blockIdx.x * 64;
    int l15 = lane & 15, l4 = lane >> 4;
    const unsigned short* tia = TI + ((size_t)t * B_ + m0) * HE;
    const unsigned short* wta = WtT + (size_t)t * NO * HE;
    #pragma unroll
    for (int it = 0; it < 8; ++it) {
        int c = tid + it * 256;
        int row = c >> 5, kc = (c & 31) * 8;
        *(uint4*)(&As[row][kc]) = *(const uint4*)(tia + (size_t)row * HE + kc);
        *(uint4*)(&Ws[row][kc]) = *(const uint4*)(wta + (size_t)row * HE + kc);
    }
    __syncthreads();
    f32x4 acc[4];
    f32x4 z = {0, 0, 0, 0};
    for (int i = 0; i < 4; ++i) acc[i] = z;
    int wsub = wav * 16;
    #pragma unroll
    for (int kk = 0; kk < 8; ++kk) {
        int kcol = kk * 32 + l4 * 8;
        short8 a = *(const short8*)(&As[wsub + l15][kcol]);
        #pragma unroll
        for (int nf = 0; nf < 4; ++nf) {
            short8 b = *(const short8*)(&Ws[nf * 16 + l15][kcol]);
            acc[nf] = __builtin_amdgcn_mfma_f32_16x16x32_bf16(a, b, acc[nf], 0, 0, 0);
        }
    }
    #pragma unroll
    for (int nf = 0; nf < 4; ++nf) {
        int col = nf * 16 + l15;
        float bias = bt[t * NO + col];
        #pragma unroll
        for (int r = 0; r < 4; ++r) {
            int row = m0 + wsub + l4 * 4 + r;
            float v = acc[nf][r] + bias;
            v = 1.f / (1.f + __expf(-v));
            out[(size_t)t * (B_ * NO) + (size_t)row * NO + col] = v;
        }
    }
}

extern "C" void kernel_launch(void* const* d_in, const int* in_sizes, int n_in,
                              void* d_out, int out_size, void* d_ws, size_t ws_size,
                              hipStream_t stream) {
    const float* xv = (const float*)d_in[0];
    const float* We = (const float*)d_in[1];
    const float* be = (const float*)d_in[2];
    const float* Wg = (const float*)d_in[3];
    const float* bg = (const float*)d_in[4];
    const float* Wt = (const float*)d_in[5];
    const float* bt = (const float*)d_in[6];
    float* out = (float*)d_out;

    char* w = (char*)d_ws;
    unsigned short* Xb    = (unsigned short*)(w);                 // 16 MiB
    unsigned short* Wb    = (unsigned short*)(w + 16777216);      //  2 MiB
    float*          gates = (float*)         (w + 18874368);      //  1 MiB
    unsigned short* H     = (unsigned short*)(w + 19922944);      // 64 MiB
    unsigned short* TI    = (unsigned short*)(w + 87031808);      // 16 MiB
    unsigned short* WtT   = (unsigned short*)(w + 103809024);     // 64 KiB

    k_cvt_x<<<4096, 256, 0, stream>>>(xv, Xb);
    k_cvt_we<<<256, 256, 0, stream>>>(We, Wb);
    k_cvt_wt<<<8, 256, 0, stream>>>(Wt, WtT);
    k_gates<<<1024, 256, 0, stream>>>(xv, Wg, bg, gates);
    dim3 g4(16, 128);
    k_experts<<<g4, 256, 0, stream>>>(Xb, Wb, be, H);
    k_mix<<<4096, 256, 0, stream>>>(H, gates, TI);
    dim3 g5(256, 2);
    k_tower<<<g5, 256, 0, stream>>>(TI, WtT, bt, out);
}

// Round 4
// 107.217 us; speedup vs baseline: 1.2283x; 1.2283x over previous
//
#include <hip/hip_runtime.h>
#include <hip/hip_bf16.h>

#define B_   16384
#define KIN  512
#define NE   8
#define HE   256
#define NT   2
#define NO   64
#define NCOL 2048  // NE*HE

using f32x4  = __attribute__((ext_vector_type(4))) float;
using short8 = __attribute__((ext_vector_type(8))) short;

typedef const __attribute__((address_space(1))) void* gas_ptr;
typedef __attribute__((address_space(3))) void* las_ptr;

__device__ __forceinline__ float bf2f(unsigned short u) {
    union { unsigned int i; float f; } c; c.i = ((unsigned int)u) << 16; return c.f;
}
__device__ __forceinline__ unsigned short f2bf(float f) {
    union { __hip_bfloat16 h; unsigned short u; } c; c.h = __float2bfloat16(f); return c.u;
}

// ---------------- K1: X fp32 -> bf16 ----------------
__global__ __launch_bounds__(256) void k_cvt_x(const float* __restrict__ x,
                                               unsigned short* __restrict__ xb) {
    int i = blockIdx.x * 256 + threadIdx.x;          // 8-elem chunk id
    const float4* x4 = (const float4*)x;
    float4 a = x4[2 * i], b = x4[2 * i + 1];
    union { uint4 v; unsigned short s[8]; } o;
    o.s[0] = f2bf(a.x); o.s[1] = f2bf(a.y); o.s[2] = f2bf(a.z); o.s[3] = f2bf(a.w);
    o.s[4] = f2bf(b.x); o.s[5] = f2bf(b.y); o.s[6] = f2bf(b.z); o.s[7] = f2bf(b.w);
    ((uint4*)xb)[i] = o.v;
}

// ---------------- K2: We [E][K][H] fp32 -> Wb [E*H][K] bf16 (transpose) ----------------
__global__ __launch_bounds__(256) void k_cvt_we(const float* __restrict__ We,
                                                unsigned short* __restrict__ Wb) {
    __shared__ float tile[64][65];
    int bid = blockIdx.x;
    int e = bid >> 5, rem = bid & 31, kt = rem >> 2, ht = rem & 3;
    int tid = threadIdx.x;
    const float* src = We + e * (KIN * HE) + (kt * 64) * HE + ht * 64;
    for (int it = 0; it < 16; ++it) {
        int idx = tid + it * 256;
        int i = idx >> 6, j = idx & 63;              // i = k-sub, j = h-sub
        tile[i][j] = src[i * HE + j];
    }
    __syncthreads();
    unsigned short* dst = Wb + (size_t)(e * HE + ht * 64) * KIN + kt * 64;
    for (int it = 0; it < 16; ++it) {
        int idx = tid + it * 256;
        int i = idx >> 6, j = idx & 63;              // i = h-sub, j = k-sub
        dst[i * KIN + j] = f2bf(tile[j][i]);
    }
}

// ---------------- K2b: Wt -> WtT bf16 [T][NO][HE]; block 8: Wg -> WgT bf16 [16][KIN] ----------------
__global__ __launch_bounds__(256) void k_cvt_wtg(const float* __restrict__ Wt,
                                                 const float* __restrict__ Wg,
                                                 unsigned short* __restrict__ WtT,
                                                 unsigned short* __restrict__ WgT) {
    int bid = blockIdx.x;
    int tid = threadIdx.x;
    if (bid < 8) {
        __shared__ float tile[64][65];
        int t = bid >> 2, kt = bid & 3, k0 = kt * 64;
        const float* src = Wt + t * (HE * NO) + k0 * NO;
        for (int it = 0; it < 16; ++it) {
            int idx = tid + it * 256;
            int i = idx >> 6, j = idx & 63;          // i = k-sub, j = o
            tile[i][j] = src[i * NO + j];
        }
        __syncthreads();
        unsigned short* dst = WtT + (size_t)t * NO * HE + k0;
        for (int it = 0; it < 16; ++it) {
            int idx = tid + it * 256;
            int o = idx >> 6, j = idx & 63;          // o-row, j = k-sub
            dst[o * HE + j] = f2bf(tile[j][o]);
        }
    } else {
        // WgT[n][k] = Wg[t][k][e], n = t*8+e;  16 x 512
        int n = tid >> 4;                            // 0..15
        int kb = (tid & 15) * 32;                    // k base
        int t = n >> 3, e = n & 7;
        const float* src = Wg + t * (KIN * NE) + e;
        for (int j = 0; j < 32; ++j) {
            int k = kb + j;
            WgT[n * KIN + k] = f2bf(src[k * NE]);
        }
    }
}

// ---------------- K3: gates via MFMA: softmax(Xb @ WgT^T + bg) -> [B][16] fp32 ----------------
__global__ __launch_bounds__(256) void k_gates_mfma(const unsigned short* __restrict__ Xb,
                                                    const unsigned short* __restrict__ WgT,
                                                    const float* __restrict__ bg,
                                                    float* __restrict__ gates) {
    int tid = threadIdx.x, lane = tid & 63, wav = tid >> 6;
    int l15 = lane & 15, l4 = lane >> 4;
    int m0 = blockIdx.x * 64 + wav * 16;
    f32x4 acc = {0.f, 0.f, 0.f, 0.f};
    #pragma unroll
    for (int kk = 0; kk < 16; ++kk) {
        int k = kk * 32 + l4 * 8;
        short8 a = *(const short8*)(Xb + (size_t)(m0 + l15) * KIN + k);
        short8 b = *(const short8*)(WgT + (size_t)l15 * KIN + k);
        acc = __builtin_amdgcn_mfma_f32_16x16x32_bf16(a, b, acc, 0, 0, 0);
    }
    float bias = bg[l15];
    #pragma unroll
    for (int r = 0; r < 4; ++r) {
        float v = acc[r] + bias;
        float m = v;
        m = fmaxf(m, __shfl_xor(m, 1));
        m = fmaxf(m, __shfl_xor(m, 2));
        m = fmaxf(m, __shfl_xor(m, 4));
        float p = __expf(v - m);
        float s = p;
        s += __shfl_xor(s, 1);
        s += __shfl_xor(s, 2);
        s += __shfl_xor(s, 4);
        int row = m0 + l4 * 4 + r;
        gates[row * 16 + l15] = p / s;
    }
}

// ---------------- K4: experts GEMM (m97 structure: global_load_lds w16, linear LDS) ----------------
__global__ __launch_bounds__(256) void k_experts(const unsigned short* __restrict__ Xb,
                                                 const unsigned short* __restrict__ Wb,
                                                 const float* __restrict__ be,
                                                 unsigned short* __restrict__ H) {
    __shared__ __align__(16) unsigned short As[128 * 64];
    __shared__ __align__(16) unsigned short Bs[128 * 64];
    int tid = threadIdx.x;
    int lane = tid & 63, wav = tid >> 6;
    int wr = wav >> 1, wc = wav & 1;
    int m0 = blockIdx.y * 128, n0 = blockIdx.x * 128;
    int l15 = lane & 15, l4 = lane >> 4;
    int srow = lane >> 3, scol = (lane & 7) * 8;    // staging: 8 rows x 64 cols per instr

    f32x4 acc[4][4];
    f32x4 z = {0.f, 0.f, 0.f, 0.f};
    #pragma unroll
    for (int i = 0; i < 4; ++i)
        #pragma unroll
        for (int j = 0; j < 4; ++j) acc[i][j] = z;

    const unsigned short* Ag = Xb + (size_t)m0 * KIN;
    const unsigned short* Bg = Wb + (size_t)n0 * KIN;

    for (int kt = 0; kt < 8; ++kt) {
        int k0 = kt * 64;
        __syncthreads();
        #pragma unroll
        for (int it = 0; it < 4; ++it) {
            int q = wav * 4 + it;                    // 0..15, rows 8q..8q+7
            int row = q * 8 + srow;
            __builtin_amdgcn_global_load_lds(
                (gas_ptr)(Ag + (size_t)row * KIN + k0 + scol),
                (las_ptr)(&As[q * 8 * 64]), 16, 0, 0);
            __builtin_amdgcn_global_load_lds(
                (gas_ptr)(Bg + (size_t)row * KIN + k0 + scol),
                (las_ptr)(&Bs[q * 8 * 64]), 16, 0, 0);
        }
        __syncthreads();
        #pragma unroll
        for (int kk = 0; kk < 2; ++kk) {
            short8 a[4], b[4];
            int kcol = kk * 32 + l4 * 8;
            #pragma unroll
            for (int mf = 0; mf < 4; ++mf)
                a[mf] = *(const short8*)(&As[(wr * 64 + mf * 16 + l15) * 64 + kcol]);
            #pragma unroll
            for (int nf = 0; nf < 4; ++nf)
                b[nf] = *(const short8*)(&Bs[(wc * 64 + nf * 16 + l15) * 64 + kcol]);
            #pragma unroll
            for (int mf = 0; mf < 4; ++mf)
                #pragma unroll
                for (int nf = 0; nf < 4; ++nf)
                    acc[mf][nf] = __builtin_amdgcn_mfma_f32_16x16x32_bf16(a[mf], b[nf], acc[mf][nf], 0, 0, 0);
        }
    }
    #pragma unroll
    for (int nf = 0; nf < 4; ++nf) {
        int col = n0 + wc * 64 + nf * 16 + l15;
        float bias = be[col];
        #pragma unroll
        for (int mf = 0; mf < 4; ++mf) {
            int rbase = m0 + wr * 64 + mf * 16 + l4 * 4;
            #pragma unroll
            for (int r = 0; r < 4; ++r) {
                float v = acc[mf][nf][r] + bias;
                v = fmaxf(v, 0.f);
                H[(size_t)(rbase + r) * NCOL + col] = f2bf(v);
            }
        }
    }
}

// ---------------- K5: fused mix + tower ----------------
// Per block: 64 rows. mix -> TI in LDS (bf16), tower MFMA from LDS, sigmoid, store.
__global__ __launch_bounds__(256) void k_mixtower(const unsigned short* __restrict__ H,
                                                  const float* __restrict__ gates,
                                                  const unsigned short* __restrict__ WtT,
                                                  const float* __restrict__ bt,
                                                  float* __restrict__ out) {
    __shared__ __align__(16) unsigned short TIs[2][64][264];   // padded: +8 bf16
    __shared__ float gs[64][16];
    int tid = threadIdx.x, lane = tid & 63, wav = tid >> 6;
    int r0 = blockIdx.x * 64;

    // gates -> LDS (64 rows x 16)
    {
        float4 g = ((const float4*)(gates + (size_t)r0 * 16))[tid];
        *(float4*)((float*)gs + tid * 4) = g;
    }
    __syncthreads();

    // mix: 8 passes x 8 rows; thread = (row_sub, h-chunk of 8)
    int hc = tid & 31;
    int rsb = tid >> 5;
    for (int p = 0; p < 8; ++p) {
        int rs = p * 8 + rsb;
        const uint4* hrow = (const uint4*)(H + (size_t)(r0 + rs) * NCOL);
        float a0[8] = {0, 0, 0, 0, 0, 0, 0, 0};
        float a1[8] = {0, 0, 0, 0, 0, 0, 0, 0};
        #pragma unroll
        for (int e = 0; e < 8; ++e) {
            uint4 v = hrow[e * 32 + hc];
            float g0 = gs[rs][e], g1 = gs[rs][8 + e];
            unsigned short* s = (unsigned short*)&v;
            #pragma unroll
            for (int j = 0; j < 8; ++j) {
                float h = bf2f(s[j]);
                a0[j] += g0 * h;
                a1[j] += g1 * h;
            }
        }
        union { uint4 v; unsigned short s[8]; } o0, o1;
        #pragma unroll
        for (int j = 0; j < 8; ++j) { o0.s[j] = f2bf(a0[j]); o1.s[j] = f2bf(a1[j]); }
        *(uint4*)(&TIs[0][rs][hc * 8]) = o0.v;
        *(uint4*)(&TIs[1][rs][hc * 8]) = o1.v;
    }
    __syncthreads();

    // tower: wave -> 16 rows, both tasks; N=64, K=256
    int l15 = lane & 15, l4 = lane >> 4;
    #pragma unroll
    for (int t = 0; t < 2; ++t) {
        f32x4 acc[4];
        f32x4 z = {0.f, 0.f, 0.f, 0.f};
        #pragma unroll
        for (int nf = 0; nf < 4; ++nf) acc[nf] = z;
        #pragma unroll
        for (int kk = 0; kk < 8; ++kk) {
            int kcol = kk * 32 + l4 * 8;
            short8 a = *(const short8*)(&TIs[t][wav * 16 + l15][kcol]);
            #pragma unroll
            for (int nf = 0; nf < 4; ++nf) {
                short8 b = *(const short8*)(WtT + ((size_t)t * NO + nf * 16 + l15) * HE + kcol);
                acc[nf] = __builtin_amdgcn_mfma_f32_16x16x32_bf16(a, b, acc[nf], 0, 0, 0);
            }
        }
        #pragma unroll
        for (int nf = 0; nf < 4; ++nf) {
            int col = nf * 16 + l15;
            float bias = bt[t * NO + col];
            #pragma unroll
            for (int r = 0; r < 4; ++r) {
                int row = r0 + wav * 16 + l4 * 4 + r;
                float v = acc[nf][r] + bias;
                v = 1.f / (1.f + __expf(-v));
                out[(size_t)t * (B_ * NO) + (size_t)row * NO + col] = v;
            }
        }
    }
}

extern "C" void kernel_launch(void* const* d_in, const int* in_sizes, int n_in,
                              void* d_out, int out_size, void* d_ws, size_t ws_size,
                              hipStream_t stream) {
    const float* xv = (const float*)d_in[0];
    const float* We = (const float*)d_in[1];
    const float* be = (const float*)d_in[2];
    const float* Wg = (const float*)d_in[3];
    const float* bg = (const float*)d_in[4];
    const float* Wt = (const float*)d_in[5];
    const float* bt = (const float*)d_in[6];
    float* out = (float*)d_out;

    char* w = (char*)d_ws;
    unsigned short* Xb    = (unsigned short*)(w);                 // 16 MiB
    unsigned short* Wb    = (unsigned short*)(w + 16777216);      //  2 MiB
    float*          gates = (float*)         (w + 18874368);      //  1 MiB
    unsigned short* H     = (unsigned short*)(w + 19922944);      // 64 MiB
    unsigned short* WtT   = (unsigned short*)(w + 87031808);      // 64 KiB
    unsigned short* WgT   = (unsigned short*)(w + 87097344);      // 16 KiB

    k_cvt_x<<<4096, 256, 0, stream>>>(xv, Xb);
    k_cvt_we<<<256, 256, 0, stream>>>(We, Wb);
    k_cvt_wtg<<<9, 256, 0, stream>>>(Wt, Wg, WtT, WgT);
    k_gates_mfma<<<256, 256, 0, stream>>>(Xb, WgT, bg, gates);
    dim3 g4(16, 128);
    k_experts<<<g4, 256, 0, stream>>>(Xb, Wb, be, H);
    k_mixtower<<<256, 256, 0, stream>>>(H, gates, WtT, bt, out);
}

// Round 5
// 98.778 us; speedup vs baseline: 1.3332x; 1.0854x over previous
//
#include <hip/hip_runtime.h>
#include <hip/hip_bf16.h>

#define B_   16384
#define KIN  512
#define NE   8
#define HE   256
#define NT   2
#define NO   64
#define NCOL 2048  // NE*HE

using f32x4  = __attribute__((ext_vector_type(4))) float;
using short8 = __attribute__((ext_vector_type(8))) short;

typedef const __attribute__((address_space(1))) void* gas_ptr;
typedef __attribute__((address_space(3))) void* las_ptr;

__device__ __forceinline__ float bf2f(unsigned short u) {
    union { unsigned int i; float f; } c; c.i = ((unsigned int)u) << 16; return c.f;
}
__device__ __forceinline__ unsigned short f2bf(float f) {
    union { __hip_bfloat16 h; unsigned short u; } c; c.h = __float2bfloat16(f); return c.u;
}

// ---------------- K1: X fp32 -> bf16 ----------------
__global__ __launch_bounds__(256) void k_cvt_x(const float* __restrict__ x,
                                               unsigned short* __restrict__ xb) {
    int i = blockIdx.x * 256 + threadIdx.x;          // 8-elem chunk id
    const float4* x4 = (const float4*)x;
    float4 a = x4[2 * i], b = x4[2 * i + 1];
    union { uint4 v; unsigned short s[8]; } o;
    o.s[0] = f2bf(a.x); o.s[1] = f2bf(a.y); o.s[2] = f2bf(a.z); o.s[3] = f2bf(a.w);
    o.s[4] = f2bf(b.x); o.s[5] = f2bf(b.y); o.s[6] = f2bf(b.z); o.s[7] = f2bf(b.w);
    ((uint4*)xb)[i] = o.v;
}

// ---------------- K2: We [E][K][H] fp32 -> Wb [E*H][K] bf16 (transpose) ----------------
__global__ __launch_bounds__(256) void k_cvt_we(const float* __restrict__ We,
                                                unsigned short* __restrict__ Wb) {
    __shared__ float tile[64][65];
    int bid = blockIdx.x;
    int e = bid >> 5, rem = bid & 31, kt = rem >> 2, ht = rem & 3;
    int tid = threadIdx.x;
    const float* src = We + e * (KIN * HE) + (kt * 64) * HE + ht * 64;
    for (int it = 0; it < 16; ++it) {
        int idx = tid + it * 256;
        int i = idx >> 6, j = idx & 63;              // i = k-sub, j = h-sub
        tile[i][j] = src[i * HE + j];
    }
    __syncthreads();
    unsigned short* dst = Wb + (size_t)(e * HE + ht * 64) * KIN + kt * 64;
    for (int it = 0; it < 16; ++it) {
        int idx = tid + it * 256;
        int i = idx >> 6, j = idx & 63;              // i = h-sub, j = k-sub
        dst[i * KIN + j] = f2bf(tile[j][i]);
    }
}

// ---------------- K2b: Wt -> WtT bf16 [T][NO][HE]; block 8: Wg -> WgT bf16 [16][KIN] ----------------
__global__ __launch_bounds__(256) void k_cvt_wtg(const float* __restrict__ Wt,
                                                 const float* __restrict__ Wg,
                                                 unsigned short* __restrict__ WtT,
                                                 unsigned short* __restrict__ WgT) {
    int bid = blockIdx.x;
    int tid = threadIdx.x;
    if (bid < 8) {
        __shared__ float tile[64][65];
        int t = bid >> 2, kt = bid & 3, k0 = kt * 64;
        const float* src = Wt + t * (HE * NO) + k0 * NO;
        for (int it = 0; it < 16; ++it) {
            int idx = tid + it * 256;
            int i = idx >> 6, j = idx & 63;          // i = k-sub, j = o
            tile[i][j] = src[i * NO + j];
        }
        __syncthreads();
        unsigned short* dst = WtT + (size_t)t * NO * HE + k0;
        for (int it = 0; it < 16; ++it) {
            int idx = tid + it * 256;
            int o = idx >> 6, j = idx & 63;          // o-row, j = k-sub
            dst[o * HE + j] = f2bf(tile[j][o]);
        }
    } else {
        // WgT[n][k] = Wg[t][k][e], n = t*8+e;  16 x 512
        int n = tid >> 4;                            // 0..15
        int kb = (tid & 15) * 32;                    // k base
        int t = n >> 3, e = n & 7;
        const float* src = Wg + t * (KIN * NE) + e;
        for (int j = 0; j < 32; ++j) {
            int k = kb + j;
            WgT[n * KIN + k] = f2bf(src[k * NE]);
        }
    }
}

// ---------------- K3: gates via MFMA: softmax(Xb @ WgT^T + bg) -> [B][16] fp32 ----------------
__global__ __launch_bounds__(256) void k_gates_mfma(const unsigned short* __restrict__ Xb,
                                                    const unsigned short* __restrict__ WgT,
                                                    const float* __restrict__ bg,
                                                    float* __restrict__ gates) {
    int tid = threadIdx.x, lane = tid & 63, wav = tid >> 6;
    int l15 = lane & 15, l4 = lane >> 4;
    int m0 = blockIdx.x * 64 + wav * 16;
    f32x4 acc = {0.f, 0.f, 0.f, 0.f};
    #pragma unroll
    for (int kk = 0; kk < 16; ++kk) {
        int k = kk * 32 + l4 * 8;
        short8 a = *(const short8*)(Xb + (size_t)(m0 + l15) * KIN + k);
        short8 b = *(const short8*)(WgT + (size_t)l15 * KIN + k);
        acc = __builtin_amdgcn_mfma_f32_16x16x32_bf16(a, b, acc, 0, 0, 0);
    }
    float bias = bg[l15];
    #pragma unroll
    for (int r = 0; r < 4; ++r) {
        float v = acc[r] + bias;
        float m = v;
        m = fmaxf(m, __shfl_xor(m, 1));
        m = fmaxf(m, __shfl_xor(m, 2));
        m = fmaxf(m, __shfl_xor(m, 4));
        float p = __expf(v - m);
        float s = p;
        s += __shfl_xor(s, 1);
        s += __shfl_xor(s, 2);
        s += __shfl_xor(s, 4);
        int row = m0 + l4 * 4 + r;
        gates[row * 16 + l15] = p / s;
    }
}

// ---------------- K4: experts GEMM (m97 structure + T2 both-sides XOR swizzle) ----------------
// LDS linear [128][64] shorts (gload_lds dest). Swizzle involution on 16B chunks:
//   stored_at(row, chunk) = data(row, chunk ^ (row&7))
// Stage side: lane l writes chunk (l&7) of row q*8+(l>>3)  -> source chunk (l&7)^(l>>3).
// Read side:  short-idx = row*64 + ((kk*32 + l4*8) ^ ((l15&7)*8)).
__global__ __launch_bounds__(256) void k_experts(const unsigned short* __restrict__ Xb,
                                                 const unsigned short* __restrict__ Wb,
                                                 const float* __restrict__ be,
                                                 unsigned short* __restrict__ H) {
    __shared__ __align__(16) unsigned short As[128 * 64];
    __shared__ __align__(16) unsigned short Bs[128 * 64];
    int tid = threadIdx.x;
    int lane = tid & 63, wav = tid >> 6;
    int wr = wav >> 1, wc = wav & 1;
    int m0 = blockIdx.y * 128, n0 = blockIdx.x * 128;
    int l15 = lane & 15, l4 = lane >> 4;
    int srow = lane >> 3;
    int scol = ((lane & 7) ^ srow) * 8;              // pre-swizzled global source chunk

    f32x4 acc[4][4];
    f32x4 z = {0.f, 0.f, 0.f, 0.f};
    #pragma unroll
    for (int i = 0; i < 4; ++i)
        #pragma unroll
        for (int j = 0; j < 4; ++j) acc[i][j] = z;

    const unsigned short* Ag = Xb + (size_t)m0 * KIN;
    const unsigned short* Bg = Wb + (size_t)n0 * KIN;

    int swz = (l15 & 7) * 8;                         // read-side XOR (shorts)

    for (int kt = 0; kt < 8; ++kt) {
        int k0 = kt * 64;
        __syncthreads();
        #pragma unroll
        for (int it = 0; it < 4; ++it) {
            int q = wav * 4 + it;                    // 0..15, rows 8q..8q+7
            int row = q * 8 + srow;
            __builtin_amdgcn_global_load_lds(
                (gas_ptr)(Ag + (size_t)row * KIN + k0 + scol),
                (las_ptr)(&As[q * 8 * 64]), 16, 0, 0);
            __builtin_amdgcn_global_load_lds(
                (gas_ptr)(Bg + (size_t)row * KIN + k0 + scol),
                (las_ptr)(&Bs[q * 8 * 64]), 16, 0, 0);
        }
        __syncthreads();
        #pragma unroll
        for (int kk = 0; kk < 2; ++kk) {
            short8 a[4], b[4];
            int kcol = (kk * 32 + l4 * 8) ^ swz;     // swizzled column (16B aligned)
            #pragma unroll
            for (int mf = 0; mf < 4; ++mf)
                a[mf] = *(const short8*)(&As[(wr * 64 + mf * 16 + l15) * 64 + kcol]);
            #pragma unroll
            for (int nf = 0; nf < 4; ++nf)
                b[nf] = *(const short8*)(&Bs[(wc * 64 + nf * 16 + l15) * 64 + kcol]);
            #pragma unroll
            for (int mf = 0; mf < 4; ++mf)
                #pragma unroll
                for (int nf = 0; nf < 4; ++nf)
                    acc[mf][nf] = __builtin_amdgcn_mfma_f32_16x16x32_bf16(a[mf], b[nf], acc[mf][nf], 0, 0, 0);
        }
    }
    #pragma unroll
    for (int nf = 0; nf < 4; ++nf) {
        int col = n0 + wc * 64 + nf * 16 + l15;
        float bias = be[col];
        #pragma unroll
        for (int mf = 0; mf < 4; ++mf) {
            int rbase = m0 + wr * 64 + mf * 16 + l4 * 4;
            #pragma unroll
            for (int r = 0; r < 4; ++r) {
                float v = acc[mf][nf][r] + bias;
                v = fmaxf(v, 0.f);
                H[(size_t)(rbase + r) * NCOL + col] = f2bf(v);
            }
        }
    }
}

// ---------------- K5: fused mix + tower ----------------
// Per block: 64 rows. mix -> TI in LDS (bf16), tower MFMA from LDS, sigmoid, store.
__global__ __launch_bounds__(256) void k_mixtower(const unsigned short* __restrict__ H,
                                                  const float* __restrict__ gates,
                                                  const unsigned short* __restrict__ WtT,
                                                  const float* __restrict__ bt,
                                                  float* __restrict__ out) {
    __shared__ __align__(16) unsigned short TIs[2][64][264];   // padded: +8 bf16
    __shared__ float gs[64][16];
    int tid = threadIdx.x, lane = tid & 63, wav = tid >> 6;
    int r0 = blockIdx.x * 64;

    // gates -> LDS (64 rows x 16)
    {
        float4 g = ((const float4*)(gates + (size_t)r0 * 16))[tid];
        *(float4*)((float*)gs + tid * 4) = g;
    }
    __syncthreads();

    // mix: 8 passes x 8 rows; thread = (row_sub, h-chunk of 8)
    int hc = tid & 31;
    int rsb = tid >> 5;
    for (int p = 0; p < 8; ++p) {
        int rs = p * 8 + rsb;
        const uint4* hrow = (const uint4*)(H + (size_t)(r0 + rs) * NCOL);
        float a0[8] = {0, 0, 0, 0, 0, 0, 0, 0};
        float a1[8] = {0, 0, 0, 0, 0, 0, 0, 0};
        #pragma unroll
        for (int e = 0; e < 8; ++e) {
            uint4 v = hrow[e * 32 + hc];
            float g0 = gs[rs][e], g1 = gs[rs][8 + e];
            unsigned short* s = (unsigned short*)&v;
            #pragma unroll
            for (int j = 0; j < 8; ++j) {
                float h = bf2f(s[j]);
                a0[j] += g0 * h;
                a1[j] += g1 * h;
            }
        }
        union { uint4 v; unsigned short s[8]; } o0, o1;
        #pragma unroll
        for (int j = 0; j < 8; ++j) { o0.s[j] = f2bf(a0[j]); o1.s[j] = f2bf(a1[j]); }
        *(uint4*)(&TIs[0][rs][hc * 8]) = o0.v;
        *(uint4*)(&TIs[1][rs][hc * 8]) = o1.v;
    }
    __syncthreads();

    // tower: wave -> 16 rows, both tasks; N=64, K=256
    int l15 = lane & 15, l4 = lane >> 4;
    #pragma unroll
    for (int t = 0; t < 2; ++t) {
        f32x4 acc[4];
        f32x4 z = {0.f, 0.f, 0.f, 0.f};
        #pragma unroll
        for (int nf = 0; nf < 4; ++nf) acc[nf] = z;
        #pragma unroll
        for (int kk = 0; kk < 8; ++kk) {
            int kcol = kk * 32 + l4 * 8;
            short8 a = *(const short8*)(&TIs[t][wav * 16 + l15][kcol]);
            #pragma unroll
            for (int nf = 0; nf < 4; ++nf) {
                short8 b = *(const short8*)(WtT + ((size_t)t * NO + nf * 16 + l15) * HE + kcol);
                acc[nf] = __builtin_amdgcn_mfma_f32_16x16x32_bf16(a, b, acc[nf], 0, 0, 0);
            }
        }
        #pragma unroll
        for (int nf = 0; nf < 4; ++nf) {
            int col = nf * 16 + l15;
            float bias = bt[t * NO + col];
            #pragma unroll
            for (int r = 0; r < 4; ++r) {
                int row = r0 + wav * 16 + l4 * 4 + r;
                float v = acc[nf][r] + bias;
                v = 1.f / (1.f + __expf(-v));
                out[(size_t)t * (B_ * NO) + (size_t)row * NO + col] = v;
            }
        }
    }
}

extern "C" void kernel_launch(void* const* d_in, const int* in_sizes, int n_in,
                              void* d_out, int out_size, void* d_ws, size_t ws_size,
                              hipStream_t stream) {
    const float* xv = (const float*)d_in[0];
    const float* We = (const float*)d_in[1];
    const float* be = (const float*)d_in[2];
    const float* Wg = (const float*)d_in[3];
    const float* bg = (const float*)d_in[4];
    const float* Wt = (const float*)d_in[5];
    const float* bt = (const float*)d_in[6];
    float* out = (float*)d_out;

    char* w = (char*)d_ws;
    unsigned short* Xb    = (unsigned short*)(w);                 // 16 MiB
    unsigned short* Wb    = (unsigned short*)(w + 16777216);      //  2 MiB
    float*          gates = (float*)         (w + 18874368);      //  1 MiB
    unsigned short* H     = (unsigned short*)(w + 19922944);      // 64 MiB
    unsigned short* WtT   = (unsigned short*)(w + 87031808);      // 64 KiB
    unsigned short* WgT   = (unsigned short*)(w + 87097344);      // 16 KiB

    k_cvt_x<<<4096, 256, 0, stream>>>(xv, Xb);
    k_cvt_we<<<256, 256, 0, stream>>>(We, Wb);
    k_cvt_wtg<<<9, 256, 0, stream>>>(Wt, Wg, WtT, WgT);
    k_gates_mfma<<<256, 256, 0, stream>>>(Xb, WgT, bg, gates);
    dim3 g4(16, 128);
    k_experts<<<g4, 256, 0, stream>>>(Xb, Wb, be, H);
    k_mixtower<<<256, 256, 0, stream>>>(H, gates, WtT, bt, out);
}

// Round 6
// 81.609 us; speedup vs baseline: 1.6137x; 1.2104x over previous
//
#include <hip/hip_runtime.h>
#include <hip/hip_bf16.h>

#define B_   16384
#define KIN  512
#define NE   8
#define HE   256
#define NT   2
#define NO   64
#define NCOL 2048  // NE*HE

using f32x4  = __attribute__((ext_vector_type(4))) float;
using short8 = __attribute__((ext_vector_type(8))) short;

typedef const __attribute__((address_space(1))) void* gas_ptr;
typedef __attribute__((address_space(3))) void* las_ptr;

__device__ __forceinline__ float bf2f(unsigned short u) {
    union { unsigned int i; float f; } c; c.i = ((unsigned int)u) << 16; return c.f;
}
__device__ __forceinline__ unsigned short f2bf(float f) {
    union { __hip_bfloat16 h; unsigned short u; } c; c.h = __float2bfloat16(f); return c.u;
}

// ---------------- K1: X fp32 -> bf16 ----------------
__global__ __launch_bounds__(256) void k_cvt_x(const float* __restrict__ x,
                                               unsigned short* __restrict__ xb) {
    int i = blockIdx.x * 256 + threadIdx.x;
    const float4* x4 = (const float4*)x;
    float4 a = x4[2 * i], b = x4[2 * i + 1];
    union { uint4 v; unsigned short s[8]; } o;
    o.s[0] = f2bf(a.x); o.s[1] = f2bf(a.y); o.s[2] = f2bf(a.z); o.s[3] = f2bf(a.w);
    o.s[4] = f2bf(b.x); o.s[5] = f2bf(b.y); o.s[6] = f2bf(b.z); o.s[7] = f2bf(b.w);
    ((uint4*)xb)[i] = o.v;
}

// ---------------- K2: We [E][K][H] fp32 -> Wb [E*H][K] bf16 (transpose) ----------------
__global__ __launch_bounds__(256) void k_cvt_we(const float* __restrict__ We,
                                                unsigned short* __restrict__ Wb) {
    __shared__ float tile[64][65];
    int bid = blockIdx.x;
    int e = bid >> 5, rem = bid & 31, kt = rem >> 2, ht = rem & 3;
    int tid = threadIdx.x;
    const float* src = We + e * (KIN * HE) + (kt * 64) * HE + ht * 64;
    for (int it = 0; it < 16; ++it) {
        int idx = tid + it * 256;
        int i = idx >> 6, j = idx & 63;
        tile[i][j] = src[i * HE + j];
    }
    __syncthreads();
    unsigned short* dst = Wb + (size_t)(e * HE + ht * 64) * KIN + kt * 64;
    for (int it = 0; it < 16; ++it) {
        int idx = tid + it * 256;
        int i = idx >> 6, j = idx & 63;
        dst[i * KIN + j] = f2bf(tile[j][i]);
    }
}

// ---------------- K2b: Wt -> WtT bf16 [T][NO][HE]; block 8: Wg -> WgT bf16 [16][KIN] ----------------
__global__ __launch_bounds__(256) void k_cvt_wtg(const float* __restrict__ Wt,
                                                 const float* __restrict__ Wg,
                                                 unsigned short* __restrict__ WtT,
                                                 unsigned short* __restrict__ WgT) {
    int bid = blockIdx.x;
    int tid = threadIdx.x;
    if (bid < 8) {
        __shared__ float tile[64][65];
        int t = bid >> 2, kt = bid & 3, k0 = kt * 64;
        const float* src = Wt + t * (HE * NO) + k0 * NO;
        for (int it = 0; it < 16; ++it) {
            int idx = tid + it * 256;
            int i = idx >> 6, j = idx & 63;
            tile[i][j] = src[i * NO + j];
        }
        __syncthreads();
        unsigned short* dst = WtT + (size_t)t * NO * HE + k0;
        for (int it = 0; it < 16; ++it) {
            int idx = tid + it * 256;
            int o = idx >> 6, j = idx & 63;
            dst[o * HE + j] = f2bf(tile[j][o]);
        }
    } else {
        int n = tid >> 4;
        int kb = (tid & 15) * 32;
        int t = n >> 3, e = n & 7;
        const float* src = Wg + t * (KIN * NE) + e;
        for (int j = 0; j < 32; ++j) {
            int k = kb + j;
            WgT[n * KIN + k] = f2bf(src[k * NE]);
        }
    }
}

// ---------------- K_MEGA: gates + experts + mix + tower, fused ----------------
// Block: 64-row stripe, 512 threads (8 waves). Grid 256 = 1 block/CU.
// LDS: Xs [64][512] bf16 (64K, swizzled) | Bs 2x[256][64] bf16 (64K, swizzled) | gs [64][16] f32 (4K)
// TIs [2][64][264] bf16 (67.6K) overlays Xs after expert loop.
__global__ __launch_bounds__(512, 2) void k_mega(const unsigned short* __restrict__ Xb,
                                                 const unsigned short* __restrict__ Wb,
                                                 const float* __restrict__ be,
                                                 const unsigned short* __restrict__ WgT,
                                                 const float* __restrict__ bg,
                                                 const unsigned short* __restrict__ WtT,
                                                 const float* __restrict__ bt,
                                                 float* __restrict__ out) {
    __shared__ __align__(16) char smem[135168];
    unsigned short* Xs  = (unsigned short*)smem;             // 65536 B
    unsigned short* Bs  = (unsigned short*)(smem + 65536);   // 65536 B (2 bufs)
    float*          gs  = (float*)(smem + 131072);           // 4096 B
    unsigned short* TIs = (unsigned short*)smem;             // overlay, 67584 B

    int tid = threadIdx.x, lane = tid & 63, wav = tid >> 6;
    int l15 = lane & 15, l4 = lane >> 4;
    int swz = (l15 & 7) * 8;                 // read-side XOR (shorts)
    int wv32 = wav * 32;                     // wave's h-col slice
    int r0 = blockIdx.x * 64;

    // staging lane decomposition for B tiles
    int row_off = lane >> 3;                 // 0..7
    int sco = ((lane & 7) ^ row_off) * 8;    // pre-swizzled source chunk (shorts)

    auto stage_b = [&](int s) {
        int e = s >> 3, kt = s & 7, b = s & 1;
        const unsigned short* Wbase = Wb + (size_t)(e * 256) * KIN + kt * 64;
        #pragma unroll
        for (int i = 0; i < 4; ++i) {
            int rb = i * 64 + wav * 8;
            __builtin_amdgcn_global_load_lds(
                (gas_ptr)(Wbase + (size_t)(rb + row_off) * KIN + sco),
                (las_ptr)(Bs + b * 16384 + rb * 64), 16, 0, 0);
        }
    };

    // ---- prologue: stage Xs (full 64x512, once) + B tiles s=0, s=1
    #pragma unroll
    for (int i = 0; i < 8; ++i) {
        int row = i * 8 + wav;
        __builtin_amdgcn_global_load_lds(
            (gas_ptr)(Xb + (size_t)(r0 + row) * KIN + ((lane ^ (row & 7)) * 8)),
            (las_ptr)(Xs + row * KIN), 16, 0, 0);
    }
    stage_b(0);
    stage_b(1);
    __syncthreads();

    // ---- gates: softmax(X @ WgT^T + bg) -> gs LDS  (waves w and w+4 duplicate)
    {
        int m0w = (wav & 3) * 16;
        f32x4 ga = {0.f, 0.f, 0.f, 0.f};
        #pragma unroll
        for (int kk = 0; kk < 16; ++kk) {
            short8 a = *(const short8*)(Xs + (m0w + l15) * KIN + ((kk * 32 + l4 * 8) ^ swz));
            short8 b = *(const short8*)(WgT + (size_t)l15 * KIN + kk * 32 + l4 * 8);
            ga = __builtin_amdgcn_mfma_f32_16x16x32_bf16(a, b, ga, 0, 0, 0);
        }
        float bias = bg[l15];
        #pragma unroll
        for (int r = 0; r < 4; ++r) {
            float v = ga[r] + bias;
            float m = v;
            m = fmaxf(m, __shfl_xor(m, 1));
            m = fmaxf(m, __shfl_xor(m, 2));
            m = fmaxf(m, __shfl_xor(m, 4));
            float p = __expf(v - m);
            float su = p;
            su += __shfl_xor(su, 1);
            su += __shfl_xor(su, 2);
            su += __shfl_xor(su, 4);
            gs[(m0w + l4 * 4 + r) * 16 + l15] = p / su;
        }
    }
    __syncthreads();

    // ---- expert loop: 64 steps (8 experts x 8 K-chunks), 2-phase double buffer
    f32x4 acc[4][2];
    f32x4 ti0[4][2], ti1[4][2];
    f32x4 z = {0.f, 0.f, 0.f, 0.f};
    #pragma unroll
    for (int mf = 0; mf < 4; ++mf)
        #pragma unroll
        for (int nf = 0; nf < 2; ++nf) { acc[mf][nf] = z; ti0[mf][nf] = z; ti1[mf][nf] = z; }

    #pragma unroll 8
    for (int s = 0; s < 64; ++s) {
        if (s >= 1 && s < 63) stage_b(s + 1);
        // compute step s from buf s&1
        {
            int k0 = (s & 7) * 64, b = s & 1;
            #pragma unroll
            for (int kk = 0; kk < 2; ++kk) {
                short8 a[4], bb[2];
                int kca = (k0 + kk * 32 + l4 * 8) ^ swz;
                int kcb = (kk * 32 + l4 * 8) ^ swz;
                #pragma unroll
                for (int mf = 0; mf < 4; ++mf)
                    a[mf] = *(const short8*)(Xs + (mf * 16 + l15) * KIN + kca);
                #pragma unroll
                for (int nf = 0; nf < 2; ++nf)
                    bb[nf] = *(const short8*)(Bs + b * 16384 + (wv32 + nf * 16 + l15) * 64 + kcb);
                #pragma unroll
                for (int mf = 0; mf < 4; ++mf)
                    #pragma unroll
                    for (int nf = 0; nf < 2; ++nf)
                        acc[mf][nf] = __builtin_amdgcn_mfma_f32_16x16x32_bf16(a[mf], bb[nf], acc[mf][nf], 0, 0, 0);
            }
        }
        if ((s & 7) == 7) {
            // fold expert e: ti[t] += g[row][t][e] * relu(acc + be)
            int e = s >> 3;
            float b0 = be[e * 256 + wv32 + l15];
            float b1 = be[e * 256 + wv32 + 16 + l15];
            #pragma unroll
            for (int mf = 0; mf < 4; ++mf) {
                #pragma unroll
                for (int r = 0; r < 4; ++r) {
                    int rloc = mf * 16 + l4 * 4 + r;
                    float g0 = gs[rloc * 16 + e];
                    float g1 = gs[rloc * 16 + 8 + e];
                    float h0 = fmaxf(acc[mf][0][r] + b0, 0.f);
                    float h1 = fmaxf(acc[mf][1][r] + b1, 0.f);
                    ti0[mf][0][r] = fmaf(g0, h0, ti0[mf][0][r]);
                    ti0[mf][1][r] = fmaf(g0, h1, ti0[mf][1][r]);
                    ti1[mf][0][r] = fmaf(g1, h0, ti1[mf][0][r]);
                    ti1[mf][1][r] = fmaf(g1, h1, ti1[mf][1][r]);
                    acc[mf][0][r] = 0.f;
                    acc[mf][1][r] = 0.f;
                }
            }
        }
        __syncthreads();
    }

    // ---- TI -> LDS (bf16), overlaying dead Xs region
    #pragma unroll
    for (int mf = 0; mf < 4; ++mf)
        #pragma unroll
        for (int nf = 0; nf < 2; ++nf)
            #pragma unroll
            for (int r = 0; r < 4; ++r) {
                int row = mf * 16 + l4 * 4 + r;
                int col = wv32 + nf * 16 + l15;
                TIs[(0 * 64 + row) * 264 + col] = f2bf(ti0[mf][nf][r]);
                TIs[(1 * 64 + row) * 264 + col] = f2bf(ti1[mf][nf][r]);
            }
    __syncthreads();

    // ---- tower: wave w -> task w>>2, rows (w&3)*16; N=64, K=256
    {
        int tt = wav >> 2, m0t = (wav & 3) * 16;
        f32x4 ac[4];
        #pragma unroll
        for (int nf = 0; nf < 4; ++nf) ac[nf] = z;
        #pragma unroll
        for (int kk = 0; kk < 8; ++kk) {
            int kcol = kk * 32 + l4 * 8;
            short8 a = *(const short8*)(TIs + ((size_t)(tt * 64 + m0t + l15)) * 264 + kcol);
            #pragma unroll
            for (int nf = 0; nf < 4; ++nf) {
                short8 b = *(const short8*)(WtT + ((size_t)tt * NO + nf * 16 + l15) * HE + kcol);
                ac[nf] = __builtin_amdgcn_mfma_f32_16x16x32_bf16(a, b, ac[nf], 0, 0, 0);
            }
        }
        #pragma unroll
        for (int nf = 0; nf < 4; ++nf) {
            int col = nf * 16 + l15;
            float bias = bt[tt * NO + col];
            #pragma unroll
            for (int r = 0; r < 4; ++r) {
                int row = r0 + m0t + l4 * 4 + r;
                float v = ac[nf][r] + bias;
                v = 1.f / (1.f + __expf(-v));
                out[(size_t)tt * (B_ * NO) + (size_t)row * NO + col] = v;
            }
        }
    }
}

extern "C" void kernel_launch(void* const* d_in, const int* in_sizes, int n_in,
                              void* d_out, int out_size, void* d_ws, size_t ws_size,
                              hipStream_t stream) {
    const float* xv = (const float*)d_in[0];
    const float* We = (const float*)d_in[1];
    const float* be = (const float*)d_in[2];
    const float* Wg = (const float*)d_in[3];
    const float* bg = (const float*)d_in[4];
    const float* Wt = (const float*)d_in[5];
    const float* bt = (const float*)d_in[6];
    float* out = (float*)d_out;

    char* w = (char*)d_ws;
    unsigned short* Xb  = (unsigned short*)(w);                 // 16 MiB
    unsigned short* Wb  = (unsigned short*)(w + 16777216);      //  2 MiB
    unsigned short* WtT = (unsigned short*)(w + 18874368);      // 64 KiB
    unsigned short* WgT = (unsigned short*)(w + 18939904);      // 16 KiB

    k_cvt_x<<<4096, 256, 0, stream>>>(xv, Xb);
    k_cvt_we<<<256, 256, 0, stream>>>(We, Wb);
    k_cvt_wtg<<<9, 256, 0, stream>>>(Wt, Wg, WtT, WgT);
    k_mega<<<256, 512, 0, stream>>>(Xb, Wb, be, WgT, bg, WtT, bt, out);
}

// Round 7
// 78.563 us; speedup vs baseline: 1.6763x; 1.0388x over previous
//
#include <hip/hip_runtime.h>
#include <hip/hip_bf16.h>

#define B_   16384
#define KIN  512
#define NE   8
#define HE   256
#define NT   2
#define NO   64
#define NCOL 2048  // NE*HE

using f32x4  = __attribute__((ext_vector_type(4))) float;
using short8 = __attribute__((ext_vector_type(8))) short;

typedef const __attribute__((address_space(1))) void* gas_ptr;
typedef __attribute__((address_space(3))) void* las_ptr;

__device__ __forceinline__ float bf2f(unsigned short u) {
    union { unsigned int i; float f; } c; c.i = ((unsigned int)u) << 16; return c.f;
}
__device__ __forceinline__ unsigned short f2bf(float f) {
    union { __hip_bfloat16 h; unsigned short u; } c; c.h = __float2bfloat16(f); return c.u;
}

// ---------------- K1: X fp32 -> bf16 ----------------
__global__ __launch_bounds__(256) void k_cvt_x(const float* __restrict__ x,
                                               unsigned short* __restrict__ xb) {
    int i = blockIdx.x * 256 + threadIdx.x;
    const float4* x4 = (const float4*)x;
    float4 a = x4[2 * i], b = x4[2 * i + 1];
    union { uint4 v; unsigned short s[8]; } o;
    o.s[0] = f2bf(a.x); o.s[1] = f2bf(a.y); o.s[2] = f2bf(a.z); o.s[3] = f2bf(a.w);
    o.s[4] = f2bf(b.x); o.s[5] = f2bf(b.y); o.s[6] = f2bf(b.z); o.s[7] = f2bf(b.w);
    ((uint4*)xb)[i] = o.v;
}

// ---------------- K2: We [E][K][H] fp32 -> Wb [E*H][K] bf16 (transpose) ----------------
__global__ __launch_bounds__(256) void k_cvt_we(const float* __restrict__ We,
                                                unsigned short* __restrict__ Wb) {
    __shared__ float tile[64][65];
    int bid = blockIdx.x;
    int e = bid >> 5, rem = bid & 31, kt = rem >> 2, ht = rem & 3;
    int tid = threadIdx.x;
    const float* src = We + e * (KIN * HE) + (kt * 64) * HE + ht * 64;
    for (int it = 0; it < 16; ++it) {
        int idx = tid + it * 256;
        int i = idx >> 6, j = idx & 63;
        tile[i][j] = src[i * HE + j];
    }
    __syncthreads();
    unsigned short* dst = Wb + (size_t)(e * HE + ht * 64) * KIN + kt * 64;
    for (int it = 0; it < 16; ++it) {
        int idx = tid + it * 256;
        int i = idx >> 6, j = idx & 63;
        dst[i * KIN + j] = f2bf(tile[j][i]);
    }
}

// ---------------- K2b: Wt -> WtT bf16 [T][NO][HE]; block 8: Wg -> WgT bf16 [16][KIN] ----------------
__global__ __launch_bounds__(256) void k_cvt_wtg(const float* __restrict__ Wt,
                                                 const float* __restrict__ Wg,
                                                 unsigned short* __restrict__ WtT,
                                                 unsigned short* __restrict__ WgT) {
    int bid = blockIdx.x;
    int tid = threadIdx.x;
    if (bid < 8) {
        __shared__ float tile[64][65];
        int t = bid >> 2, kt = bid & 3, k0 = kt * 64;
        const float* src = Wt + t * (HE * NO) + k0 * NO;
        for (int it = 0; it < 16; ++it) {
            int idx = tid + it * 256;
            int i = idx >> 6, j = idx & 63;
            tile[i][j] = src[i * NO + j];
        }
        __syncthreads();
        unsigned short* dst = WtT + (size_t)t * NO * HE + k0;
        for (int it = 0; it < 16; ++it) {
            int idx = tid + it * 256;
            int o = idx >> 6, j = idx & 63;
            dst[o * HE + j] = f2bf(tile[j][o]);
        }
    } else {
        int n = tid >> 4;
        int kb = (tid & 15) * 32;
        int t = n >> 3, e = n & 7;
        const float* src = Wg + t * (KIN * NE) + e;
        for (int j = 0; j < 32; ++j) {
            int k = kb + j;
            WgT[n * KIN + k] = f2bf(src[k * NE]);
        }
    }
}

// ---------------- K_MEGA: gates + experts + mix + tower, fused ----------------
// Pipelined expert loop: counted vmcnt(4) + raw s_barrier (T3/T4) + setprio (T5).
// LDS: Xs [64][512] bf16 (64K, swizzled) | Bs 2x[256][64] bf16 (64K, swizzled)
//      gs [64][17] f32 (4.25K, padded -> conflict-free fold reads)
// TIs [2][64][264] bf16 overlays Xs+Bs after expert loop.
__global__ __launch_bounds__(512, 2) void k_mega(const unsigned short* __restrict__ Xb,
                                                 const unsigned short* __restrict__ Wb,
                                                 const float* __restrict__ be,
                                                 const unsigned short* __restrict__ WgT,
                                                 const float* __restrict__ bg,
                                                 const unsigned short* __restrict__ WtT,
                                                 const float* __restrict__ bt,
                                                 float* __restrict__ out) {
    __shared__ __align__(16) char smem[135424];
    unsigned short* Xs  = (unsigned short*)smem;             // 65536 B
    unsigned short* Bs  = (unsigned short*)(smem + 65536);   // 65536 B (2 bufs)
    float*          gs  = (float*)(smem + 131072);           // 4352 B, row stride 17
    unsigned short* TIs = (unsigned short*)smem;             // overlay, 67584 B

    int tid = threadIdx.x, lane = tid & 63, wav = tid >> 6;
    int l15 = lane & 15, l4 = lane >> 4;
    int swz = (l15 & 7) * 8;                 // read-side XOR (shorts)
    int wv32 = wav * 32;                     // wave's h-col slice
    int r0 = blockIdx.x * 64;

    int row_off = lane >> 3;                 // 0..7
    int sco = ((lane & 7) ^ row_off) * 8;    // pre-swizzled source chunk (shorts)

    auto stage_b = [&](int s) {
        int e = s >> 3, kt = s & 7, b = s & 1;
        const unsigned short* Wbase = Wb + (size_t)(e * 256) * KIN + kt * 64;
        #pragma unroll
        for (int i = 0; i < 4; ++i) {
            int rb = i * 64 + wav * 8;
            __builtin_amdgcn_global_load_lds(
                (gas_ptr)(Wbase + (size_t)(rb + row_off) * KIN + sco),
                (las_ptr)(Bs + b * 16384 + rb * 64), 16, 0, 0);
        }
    };

    // ---- prologue: stage Xs (full 64x512, once) + B tile s=0
    #pragma unroll
    for (int i = 0; i < 8; ++i) {
        int row = i * 8 + wav;
        __builtin_amdgcn_global_load_lds(
            (gas_ptr)(Xb + (size_t)(r0 + row) * KIN + ((lane ^ (row & 7)) * 8)),
            (las_ptr)(Xs + row * KIN), 16, 0, 0);
    }
    stage_b(0);
    asm volatile("s_waitcnt vmcnt(4)" ::: "memory");   // Xs landed; b0 still in flight
    asm volatile("s_barrier" ::: "memory");

    // ---- gates: softmax(X @ WgT^T + bg) -> gs LDS  (waves w and w+4 duplicate; benign)
    {
        int m0w = (wav & 3) * 16;
        f32x4 ga = {0.f, 0.f, 0.f, 0.f};
        #pragma unroll
        for (int kk = 0; kk < 16; ++kk) {
            short8 a = *(const short8*)(Xs + (m0w + l15) * KIN + ((kk * 32 + l4 * 8) ^ swz));
            short8 b = *(const short8*)(WgT + (size_t)l15 * KIN + kk * 32 + l4 * 8);
            ga = __builtin_amdgcn_mfma_f32_16x16x32_bf16(a, b, ga, 0, 0, 0);
        }
        float bias = bg[l15];
        #pragma unroll
        for (int r = 0; r < 4; ++r) {
            float v = ga[r] + bias;
            float m = v;
            m = fmaxf(m, __shfl_xor(m, 1));
            m = fmaxf(m, __shfl_xor(m, 2));
            m = fmaxf(m, __shfl_xor(m, 4));
            float p = __expf(v - m);
            float su = p;
            su += __shfl_xor(su, 1);
            su += __shfl_xor(su, 2);
            su += __shfl_xor(su, 4);
            gs[(m0w + l4 * 4 + r) * 17 + l15] = p / su;
        }
    }
    // gs visibility handled by iter-0's lgkmcnt(0)+barrier below

    // ---- expert loop: 64 steps (8 experts x 8 K-chunks), true double buffer
    f32x4 acc[4][2];
    f32x4 ti0[4][2], ti1[4][2];
    f32x4 z = {0.f, 0.f, 0.f, 0.f};
    #pragma unroll
    for (int mf = 0; mf < 4; ++mf)
        #pragma unroll
        for (int nf = 0; nf < 2; ++nf) { acc[mf][nf] = z; ti0[mf][nf] = z; ti1[mf][nf] = z; }

    #pragma unroll 8
    for (int s = 0; s < 64; ++s) {
        if (s < 63) {
            stage_b(s + 1);                  // into buf[(s+1)&1]; guarded by prev iter's barrier#2
            // wait my 4 loads of batch s (issued last iter); batch s+1 stays in flight
            asm volatile("s_waitcnt vmcnt(4) lgkmcnt(0)" ::: "memory");
        } else {
            asm volatile("s_waitcnt vmcnt(0) lgkmcnt(0)" ::: "memory");
        }
        asm volatile("s_barrier" ::: "memory");          // barrier #1: buf[s&1] visible everywhere

        __builtin_amdgcn_s_setprio(1);
        {
            int k0 = (s & 7) * 64, b = s & 1;
            #pragma unroll
            for (int kk = 0; kk < 2; ++kk) {
                short8 a[4], bb[2];
                int kca = (k0 + kk * 32 + l4 * 8) ^ swz;
                int kcb = (kk * 32 + l4 * 8) ^ swz;
                #pragma unroll
                for (int mf = 0; mf < 4; ++mf)
                    a[mf] = *(const short8*)(Xs + (mf * 16 + l15) * KIN + kca);
                #pragma unroll
                for (int nf = 0; nf < 2; ++nf)
                    bb[nf] = *(const short8*)(Bs + b * 16384 + (wv32 + nf * 16 + l15) * 64 + kcb);
                #pragma unroll
                for (int mf = 0; mf < 4; ++mf)
                    #pragma unroll
                    for (int nf = 0; nf < 2; ++nf)
                        acc[mf][nf] = __builtin_amdgcn_mfma_f32_16x16x32_bf16(a[mf], bb[nf], acc[mf][nf], 0, 0, 0);
            }
        }
        __builtin_amdgcn_s_setprio(0);

        if ((s & 7) == 7) {
            // fold expert e: ti[t] += g[row][t][e] * relu(acc + be)
            int e = s >> 3;
            float b0 = be[e * 256 + wv32 + l15];
            float b1 = be[e * 256 + wv32 + 16 + l15];
            #pragma unroll
            for (int mf = 0; mf < 4; ++mf) {
                #pragma unroll
                for (int r = 0; r < 4; ++r) {
                    int rloc = mf * 16 + l4 * 4 + r;
                    float g0 = gs[rloc * 17 + e];
                    float g1 = gs[rloc * 17 + 8 + e];
                    float h0 = fmaxf(acc[mf][0][r] + b0, 0.f);
                    float h1 = fmaxf(acc[mf][1][r] + b1, 0.f);
                    ti0[mf][0][r] = fmaf(g0, h0, ti0[mf][0][r]);
                    ti0[mf][1][r] = fmaf(g0, h1, ti0[mf][1][r]);
                    ti1[mf][0][r] = fmaf(g1, h0, ti1[mf][0][r]);
                    ti1[mf][1][r] = fmaf(g1, h1, ti1[mf][1][r]);
                    acc[mf][0][r] = 0.f;
                    acc[mf][1][r] = 0.f;
                }
            }
        }
        // barrier #2: my LDS reads complete -> next iter may overwrite buf[s&1]
        asm volatile("s_waitcnt lgkmcnt(0)" ::: "memory");
        asm volatile("s_barrier" ::: "memory");
    }

    // ---- TI -> LDS (bf16), overlaying dead Xs/Bs region
    #pragma unroll
    for (int mf = 0; mf < 4; ++mf)
        #pragma unroll
        for (int nf = 0; nf < 2; ++nf)
            #pragma unroll
            for (int r = 0; r < 4; ++r) {
                int row = mf * 16 + l4 * 4 + r;
                int col = wv32 + nf * 16 + l15;
                TIs[(0 * 64 + row) * 264 + col] = f2bf(ti0[mf][nf][r]);
                TIs[(1 * 64 + row) * 264 + col] = f2bf(ti1[mf][nf][r]);
            }
    __syncthreads();

    // ---- tower: wave w -> task w>>2, rows (w&3)*16; N=64, K=256
    {
        int tt = wav >> 2, m0t = (wav & 3) * 16;
        f32x4 ac[4];
        #pragma unroll
        for (int nf = 0; nf < 4; ++nf) ac[nf] = z;
        #pragma unroll
        for (int kk = 0; kk < 8; ++kk) {
            int kcol = kk * 32 + l4 * 8;
            short8 a = *(const short8*)(TIs + ((size_t)(tt * 64 + m0t + l15)) * 264 + kcol);
            #pragma unroll
            for (int nf = 0; nf < 4; ++nf) {
                short8 b = *(const short8*)(WtT + ((size_t)tt * NO + nf * 16 + l15) * HE + kcol);
                ac[nf] = __builtin_amdgcn_mfma_f32_16x16x32_bf16(a, b, ac[nf], 0, 0, 0);
            }
        }
        #pragma unroll
        for (int nf = 0; nf < 4; ++nf) {
            int col = nf * 16 + l15;
            float bias = bt[tt * NO + col];
            #pragma unroll
            for (int r = 0; r < 4; ++r) {
                int row = r0 + m0t + l4 * 4 + r;
                float v = ac[nf][r] + bias;
                v = 1.f / (1.f + __expf(-v));
                out[(size_t)tt * (B_ * NO) + (size_t)row * NO + col] = v;
            }
        }
    }
}

extern "C" void kernel_launch(void* const* d_in, const int* in_sizes, int n_in,
                              void* d_out, int out_size, void* d_ws, size_t ws_size,
                              hipStream_t stream) {
    const float* xv = (const float*)d_in[0];
    const float* We = (const float*)d_in[1];
    const float* be = (const float*)d_in[2];
    const float* Wg = (const float*)d_in[3];
    const float* bg = (const float*)d_in[4];
    const float* Wt = (const float*)d_in[5];
    const float* bt = (const float*)d_in[6];
    float* out = (float*)d_out;

    char* w = (char*)d_ws;
    unsigned short* Xb  = (unsigned short*)(w);                 // 16 MiB
    unsigned short* Wb  = (unsigned short*)(w + 16777216);      //  2 MiB
    unsigned short* WtT = (unsigned short*)(w + 18874368);      // 64 KiB
    unsigned short* WgT = (unsigned short*)(w + 18939904);      // 16 KiB

    k_cvt_x<<<4096, 256, 0, stream>>>(xv, Xb);
    k_cvt_we<<<256, 256, 0, stream>>>(We, Wb);
    k_cvt_wtg<<<9, 256, 0, stream>>>(Wt, Wg, WtT, WgT);
    k_mega<<<256, 512, 0, stream>>>(Xb, Wb, be, WgT, bg, WtT, bt, out);
}

// Round 10
// 62.012 us; speedup vs baseline: 2.1237x; 1.2669x over previous
//
#include <hip/hip_runtime.h>
#include <hip/hip_bf16.h>

#define B_   16384
#define KIN  512
#define NE   8
#define HE   256
#define NT   2
#define NO   64

using f32x4  = __attribute__((ext_vector_type(4))) float;
using short8 = __attribute__((ext_vector_type(8))) short;

typedef const __attribute__((address_space(1))) void* gas_ptr;
typedef __attribute__((address_space(3))) void* las_ptr;

__device__ __forceinline__ float bf2f(unsigned short u) {
    union { unsigned int i; float f; } c; c.i = ((unsigned int)u) << 16; return c.f;
}
__device__ __forceinline__ unsigned short f2bf(float f) {
    union { __hip_bfloat16 h; unsigned short u; } c; c.h = __float2bfloat16(f); return c.u;
}

// ---------------- K_W: all weight preprocessing in one launch ----------------
__global__ __launch_bounds__(256) void k_cvt_w(const float* __restrict__ We,
                                               const float* __restrict__ Wt,
                                               const float* __restrict__ Wg,
                                               unsigned short* __restrict__ Wb,
                                               unsigned short* __restrict__ WtT,
                                               unsigned short* __restrict__ WgT) {
    int bid = blockIdx.x;
    int tid = threadIdx.x;
    if (bid < 256) {
        __shared__ float tile[64][65];
        int e = bid >> 5, rem = bid & 31, kt = rem >> 2, ht = rem & 3;
        const float* src = We + e * (KIN * HE) + (kt * 64) * HE + ht * 64;
        for (int it = 0; it < 16; ++it) {
            int idx = tid + it * 256;
            int i = idx >> 6, j = idx & 63;
            tile[i][j] = src[i * HE + j];
        }
        __syncthreads();
        unsigned short* dst = Wb + (size_t)(e * HE + ht * 64) * KIN + kt * 64;
        for (int it = 0; it < 16; ++it) {
            int idx = tid + it * 256;
            int i = idx >> 6, j = idx & 63;
            dst[i * KIN + j] = f2bf(tile[j][i]);
        }
    } else if (bid < 264) {
        __shared__ float tile[64][65];
        int b = bid - 256;
        int t = b >> 2, kt = b & 3, k0 = kt * 64;
        const float* src = Wt + t * (HE * NO) + k0 * NO;
        for (int it = 0; it < 16; ++it) {
            int idx = tid + it * 256;
            int i = idx >> 6, j = idx & 63;
            tile[i][j] = src[i * NO + j];
        }
        __syncthreads();
        unsigned short* dst = WtT + (size_t)t * NO * HE + k0;
        for (int it = 0; it < 16; ++it) {
            int idx = tid + it * 256;
            int o = idx >> 6, j = idx & 63;
            dst[o * HE + j] = f2bf(tile[j][o]);
        }
    } else {
        int n = tid >> 4;
        int kb = (tid & 15) * 32;
        int t = n >> 3, e = n & 7;
        const float* src = Wg + t * (KIN * NE) + e;
        for (int j = 0; j < 32; ++j) {
            int k = kb + j;
            WgT[n * KIN + k] = f2bf(src[k * NE]);
        }
    }
}

// ---------------- K_MEGA: cvt_x + gates + experts + mix + tower, fused ----------------
// 64-row stripe, 512 threads (8 waves), grid 256 = 1 block/CU.
// BARRIER-FREE expert loop: each wave stages ONLY its own 32-row B slice
// (rows [wv32, wv32+32) of each [256][64] tile) -> no cross-wave Bs dependency.
// Per-wave pacing: stage(s+1) [4 gload_lds]; s_waitcnt vmcnt(4) => batch s landed.
// Ring: 2 slots x 32 KB (16384 shorts stride — r8/r9 bug was an 8192 stride,
// overlapping slots; identical absmax across sync variants = deterministic bug).
// Xs/gs are read-only after the two prologue barriers.
__global__ __launch_bounds__(512, 2) void k_mega(const float* __restrict__ xv,
                                                 const unsigned short* __restrict__ Wb,
                                                 const float* __restrict__ be,
                                                 const unsigned short* __restrict__ WgT,
                                                 const float* __restrict__ bg,
                                                 const unsigned short* __restrict__ WtT,
                                                 const float* __restrict__ bt,
                                                 float* __restrict__ out) {
    __shared__ __align__(16) char smem[135424];
    unsigned short* Xs  = (unsigned short*)smem;             // 65536 B, swizzled
    unsigned short* Bs  = (unsigned short*)(smem + 65536);   // 65536 B = 2 slots x 32KB
    float*          gs  = (float*)(smem + 131072);           // 4352 B, row stride 17
    unsigned short* TIs = (unsigned short*)smem;             // overlay after loop

    int tid = threadIdx.x, lane = tid & 63, wav = tid >> 6;
    int l15 = lane & 15, l4 = lane >> 4;
    int swz = (l15 & 7) * 8;                 // read-side XOR (shorts)
    int wv32 = wav * 32;                     // wave's h-col slice
    int r0 = blockIdx.x * 64;

    int row_off = lane >> 3;                 // 0..7
    int sco = ((lane & 7) ^ row_off) * 8;    // pre-swizzled source chunk (shorts)

    // wave stages ONLY its own 32-row slice of tile s into slot s&1
    auto stage_b = [&](int s) {
        int e = s >> 3, kt = s & 7, b = s & 1;
        const unsigned short* Wbase = Wb + (size_t)(e * 256 + wv32) * KIN + kt * 64;
        #pragma unroll
        for (int i = 0; i < 4; ++i) {
            int rb = i * 8;
            __builtin_amdgcn_global_load_lds(
                (gas_ptr)(Wbase + (size_t)(rb + row_off) * KIN + sco),
                (las_ptr)(Bs + b * 16384 + (wv32 + rb) * 64), 16, 0, 0);
        }
    };

    // ---- prologue: X fp32 -> bf16 -> swizzled LDS (reg-staged)
    #pragma unroll
    for (int j = 0; j < 8; ++j) {
        int row = wav * 8 + j;
        const float4* src = (const float4*)(xv + (size_t)(r0 + row) * KIN) + lane * 2;
        float4 xa = src[0], xb = src[1];
        union { short8 v; unsigned short s[8]; } cv;
        cv.s[0] = f2bf(xa.x); cv.s[1] = f2bf(xa.y); cv.s[2] = f2bf(xa.z); cv.s[3] = f2bf(xa.w);
        cv.s[4] = f2bf(xb.x); cv.s[5] = f2bf(xb.y); cv.s[6] = f2bf(xb.z); cv.s[7] = f2bf(xb.w);
        *(short8*)(Xs + row * KIN + ((lane ^ (row & 7)) * 8)) = cv.v;
    }
    asm volatile("s_waitcnt lgkmcnt(0)" ::: "memory");
    asm volatile("s_barrier" ::: "memory");          // Xs visible to all waves

    stage_b(0);                                      // lands during gates phase

    // ---- gates: softmax(X @ WgT^T + bg) -> gs  (waves w, w+4 duplicate; benign)
    {
        int m0w = (wav & 3) * 16;
        f32x4 ga = {0.f, 0.f, 0.f, 0.f};
        #pragma unroll
        for (int kk = 0; kk < 16; ++kk) {
            short8 a = *(const short8*)(Xs + (m0w + l15) * KIN + ((kk * 32 + l4 * 8) ^ swz));
            short8 b = *(const short8*)(WgT + (size_t)l15 * KIN + kk * 32 + l4 * 8);
            ga = __builtin_amdgcn_mfma_f32_16x16x32_bf16(a, b, ga, 0, 0, 0);
        }
        float bias = bg[l15];
        #pragma unroll
        for (int r = 0; r < 4; ++r) {
            float v = ga[r] + bias;
            float m = v;
            m = fmaxf(m, __shfl_xor(m, 1));
            m = fmaxf(m, __shfl_xor(m, 2));
            m = fmaxf(m, __shfl_xor(m, 4));
            float p = __expf(v - m);
            float su = p;
            su += __shfl_xor(su, 1);
            su += __shfl_xor(su, 2);
            su += __shfl_xor(su, 4);
            gs[(m0w + l4 * 4 + r) * 17 + l15] = p / su;
        }
    }
    asm volatile("s_waitcnt lgkmcnt(0)" ::: "memory");
    asm volatile("s_barrier" ::: "memory");          // gs visible to all waves

    // ---- expert loop state
    f32x4 acc[4][2];
    f32x4 ti0[4][2], ti1[4][2];
    f32x4 z = {0.f, 0.f, 0.f, 0.f};
    #pragma unroll
    for (int mf = 0; mf < 4; ++mf)
        #pragma unroll
        for (int nf = 0; nf < 2; ++nf) { acc[mf][nf] = z; ti0[mf][nf] = z; ti1[mf][nf] = z; }

    auto compute = [&](int s) {
        int k0 = (s & 7) * 64, b = s & 1;
        __builtin_amdgcn_s_setprio(1);
        #pragma unroll
        for (int kk = 0; kk < 2; ++kk) {
            short8 a[4], bb[2];
            int kca = (k0 + kk * 32 + l4 * 8) ^ swz;
            int kcb = (kk * 32 + l4 * 8) ^ swz;
            #pragma unroll
            for (int mf = 0; mf < 4; ++mf)
                a[mf] = *(const short8*)(Xs + (mf * 16 + l15) * KIN + kca);
            #pragma unroll
            for (int nf = 0; nf < 2; ++nf)
                bb[nf] = *(const short8*)(Bs + b * 16384 + (wv32 + nf * 16 + l15) * 64 + kcb);
            #pragma unroll
            for (int mf = 0; mf < 4; ++mf)
                #pragma unroll
                for (int nf = 0; nf < 2; ++nf)
                    acc[mf][nf] = __builtin_amdgcn_mfma_f32_16x16x32_bf16(a[mf], bb[nf], acc[mf][nf], 0, 0, 0);
        }
        __builtin_amdgcn_s_setprio(0);
    };
    auto fold = [&](int e) {
        float b0 = be[e * 256 + wv32 + l15];
        float b1 = be[e * 256 + wv32 + 16 + l15];
        #pragma unroll
        for (int mf = 0; mf < 4; ++mf) {
            #pragma unroll
            for (int r = 0; r < 4; ++r) {
                int rloc = mf * 16 + l4 * 4 + r;
                float g0 = gs[rloc * 17 + e];
                float g1 = gs[rloc * 17 + 8 + e];
                float h0 = fmaxf(acc[mf][0][r] + b0, 0.f);
                float h1 = fmaxf(acc[mf][1][r] + b1, 0.f);
                ti0[mf][0][r] = fmaf(g0, h0, ti0[mf][0][r]);
                ti0[mf][1][r] = fmaf(g0, h1, ti0[mf][1][r]);
                ti1[mf][0][r] = fmaf(g1, h0, ti1[mf][0][r]);
                ti1[mf][1][r] = fmaf(g1, h1, ti1[mf][1][r]);
                acc[mf][0][r] = 0.f;
                acc[mf][1][r] = 0.f;
            }
        }
    };

    // ---- main loop: BARRIER-FREE; per-wave counted vmcnt pacing
    #pragma unroll 8
    for (int s = 0; s < 64; ++s) {
        if (s < 63) {
            stage_b(s + 1);
            asm volatile("s_waitcnt vmcnt(4)" ::: "memory");  // batch s landed; s+1 in flight
        } else {
            asm volatile("s_waitcnt vmcnt(0)" ::: "memory");
        }
        compute(s);
        if ((s & 7) == 7) fold(s >> 3);
    }

    // ---- TI -> LDS (bf16), overlaying dead Xs/Bs
    __syncthreads();                                   // all waves done with Xs/Bs
    #pragma unroll
    for (int mf = 0; mf < 4; ++mf)
        #pragma unroll
        for (int nf = 0; nf < 2; ++nf)
            #pragma unroll
            for (int r = 0; r < 4; ++r) {
                int row = mf * 16 + l4 * 4 + r;
                int col = wv32 + nf * 16 + l15;
                TIs[(0 * 64 + row) * 264 + col] = f2bf(ti0[mf][nf][r]);
                TIs[(1 * 64 + row) * 264 + col] = f2bf(ti1[mf][nf][r]);
            }
    __syncthreads();

    // ---- tower: wave w -> task w>>2, rows (w&3)*16; N=64, K=256
    {
        int tt = wav >> 2, m0t = (wav & 3) * 16;
        f32x4 ac[4];
        #pragma unroll
        for (int nf = 0; nf < 4; ++nf) ac[nf] = z;
        #pragma unroll
        for (int kk = 0; kk < 8; ++kk) {
            int kcol = kk * 32 + l4 * 8;
            short8 a = *(const short8*)(TIs + ((size_t)(tt * 64 + m0t + l15)) * 264 + kcol);
            #pragma unroll
            for (int nf = 0; nf < 4; ++nf) {
                short8 b = *(const short8*)(WtT + ((size_t)tt * NO + nf * 16 + l15) * HE + kcol);
                ac[nf] = __builtin_amdgcn_mfma_f32_16x16x32_bf16(a, b, ac[nf], 0, 0, 0);
            }
        }
        #pragma unroll
        for (int nf = 0; nf < 4; ++nf) {
            int col = nf * 16 + l15;
            float bias = bt[tt * NO + col];
            #pragma unroll
            for (int r = 0; r < 4; ++r) {
                int row = r0 + m0t + l4 * 4 + r;
                float v = ac[nf][r] + bias;
                v = 1.f / (1.f + __expf(-v));
                out[(size_t)tt * (B_ * NO) + (size_t)row * NO + col] = v;
            }
        }
    }
}

extern "C" void kernel_launch(void* const* d_in, const int* in_sizes, int n_in,
                              void* d_out, int out_size, void* d_ws, size_t ws_size,
                              hipStream_t stream) {
    const float* xv = (const float*)d_in[0];
    const float* We = (const float*)d_in[1];
    const float* be = (const float*)d_in[2];
    const float* Wg = (const float*)d_in[3];
    const float* bg = (const float*)d_in[4];
    const float* Wt = (const float*)d_in[5];
    const float* bt = (const float*)d_in[6];
    float* out = (float*)d_out;

    char* w = (char*)d_ws;
    unsigned short* Wb  = (unsigned short*)(w);                 //  2 MiB
    unsigned short* WtT = (unsigned short*)(w + 2097152);       // 64 KiB
    unsigned short* WgT = (unsigned short*)(w + 2162688);       // 16 KiB

    k_cvt_w<<<265, 256, 0, stream>>>(We, Wt, Wg, Wb, WtT, WgT);
    k_mega<<<256, 512, 0, stream>>>(xv, Wb, be, WgT, bg, WtT, bt, out);
}